// Round 1
// baseline (848.685 us; speedup 1.0000x reference)
//
#include <hip/hip_runtime.h>
#include <math.h>

// Batched 256-point complex DFT as 16x16 four-step FFT.
// Fully wave-private: direct global<->reg streaming (64B-line coalesced),
// ONE LDS transpose pass through a per-wave slice (no __syncthreads at all),
// real/imag reuse the same slice -> 16.9 KB LDS/block.
#define FS 264  // frame slice stride in floats (16x16 tile + 8 pad: strided
                // accesses are 2-way bank aliased = free, float4 stays aligned)

__device__ __forceinline__ void dft16(float* xr, float* xi) {
  // 16-point DFT, natural-order in/out, radix-4 x radix-4.
  // Twiddles w16^k = cos(pi k/8) - i sin(pi k/8), k = b*c <= 9.
  constexpr float TWR[10] = {1.f, 0.9238795325f, 0.7071067812f, 0.3826834324f, 0.f,
                             -0.3826834324f, -0.7071067812f, -0.9238795325f, -1.f,
                             -0.9238795325f};
  constexpr float TWI[10] = {0.f, -0.3826834324f, -0.7071067812f, -0.9238795325f, -1.f,
                             -0.9238795325f, -0.7071067812f, -0.3826834324f, 0.f,
                             0.3826834324f};
  float yr[16], yi[16];
#pragma unroll
  for (int b = 0; b < 4; ++b) {
    float x0r = xr[b],      x0i = xi[b];
    float x1r = xr[b + 4],  x1i = xi[b + 4];
    float x2r = xr[b + 8],  x2i = xi[b + 8];
    float x3r = xr[b + 12], x3i = xi[b + 12];
    float t0r = x0r + x2r, t0i = x0i + x2i;
    float t1r = x0r - x2r, t1i = x0i - x2i;
    float t2r = x1r + x3r, t2i = x1i + x3i;
    float t3r = x1r - x3r, t3i = x1i - x3i;
    // store as y[c*4 + b]
    yr[0 + b]  = t0r + t2r;  yi[0 + b]  = t0i + t2i;   // c=0
    yr[8 + b]  = t0r - t2r;  yi[8 + b]  = t0i - t2i;   // c=2
    yr[4 + b]  = t1r + t3i;  yi[4 + b]  = t1i - t3r;   // c=1: t1 - i*t3
    yr[12 + b] = t1r - t3i;  yi[12 + b] = t1i + t3r;   // c=3: t1 + i*t3
  }
#pragma unroll
  for (int c = 0; c < 4; ++c) {
    float zr[4], zi[4];
#pragma unroll
    for (int b = 0; b < 4; ++b) {
      const int k = b * c;  // <= 9, compile-time after unroll
      float ar = yr[c * 4 + b], ai = yi[c * 4 + b];
      zr[b] = ar * TWR[k] - ai * TWI[k];
      zi[b] = ar * TWI[k] + ai * TWR[k];
    }
    float t0r = zr[0] + zr[2], t0i = zi[0] + zi[2];
    float t1r = zr[0] - zr[2], t1i = zi[0] - zi[2];
    float t2r = zr[1] + zr[3], t2i = zi[1] + zi[3];
    float t3r = zr[1] - zr[3], t3i = zi[1] - zi[3];
    // out[c + 4d]
    xr[c]      = t0r + t2r;  xi[c]      = t0i + t2i;   // d=0
    xr[c + 8]  = t0r - t2r;  xi[c + 8]  = t0i - t2i;   // d=2
    xr[c + 4]  = t1r + t3i;  xi[c + 4]  = t1i - t3r;   // d=1
    xr[c + 12] = t1r - t3i;  xi[c + 12] = t1i + t3r;   // d=3
  }
}

__global__ __launch_bounds__(256, 4) void dft256_kernel(
    const float* __restrict__ xr, const float* __restrict__ xi,
    float* __restrict__ out, size_t half) {
  // One slice per frame; wave w (threads 64w..64w+63) owns frames 4w..4w+3,
  // so slices are wave-private: no block barriers needed anywhere.
  __shared__ __align__(16) float s[16 * FS];
  const int t = threadIdx.x;
  const int f = t >> 4;   // local frame 0..15
  const int b = t & 15;   // column role (stage 1) == row index c (stage 2)
  const size_t frame = (size_t)blockIdx.x * 16 + f;

  // Direct global -> reg, x[16a + b]. Per wave instruction: 4 frames x 16
  // consecutive floats = 4 full 64B lines, each consumed entirely -> no
  // over-fetch; compile-time offsets a*64B fold into the load immediate.
  const float* gr = xr + frame * 256 + b;
  const float* gi = xi + frame * 256 + b;
  float vr[16], vi[16];
#pragma unroll
  for (int a = 0; a < 16; ++a) {
    vr[a] = __builtin_nontemporal_load(gr + a * 16);
    vi[a] = __builtin_nontemporal_load(gi + a * 16);
  }

  // Stage 1: column DFT-16 over a at fixed b.
  dft16(vr, vi);

  // Twiddle Z[c] = Y[c] * w256^{b c}; base via one sincos, then chained cmul.
  float swb, cwb;
  __sincosf(-6.283185307179586f * (float)b * (1.0f / 256.0f), &swb, &cwb);
  float twr = 1.f, twi = 0.f;
#pragma unroll
  for (int c = 0; c < 16; ++c) {
    float ar = vr[c], ai = vi[c];
    vr[c] = ar * twr - ai * twi;
    vi[c] = ar * twi + ai * twr;
    float ntr = twr * cwb - twi * swb;
    twi = twr * swb + twi * cwb;
    twr = ntr;
  }

  // 16x16 transpose through the wave-private slice; real then imag reuse the
  // same storage. Same-wave DS ops are pipeline-ordered; the lgkmcnt(0)
  // fences (with "memory" clobber) pin compiler order + completion across
  // the cross-lane handoff. No s_barrier is ever emitted.
  const int fb = f * FS;
  const int rbase = fb + b * 16;
  float ur[16], ui[16];
#pragma unroll
  for (int c = 0; c < 16; ++c) s[fb + c * 16 + b] = vr[c];  // 2-way banked: free
  asm volatile("s_waitcnt lgkmcnt(0)" ::: "memory");
#pragma unroll
  for (int j = 0; j < 4; ++j) {
    float4 q = *(const float4*)&s[rbase + 4 * j];
    ur[4 * j + 0] = q.x; ur[4 * j + 1] = q.y;
    ur[4 * j + 2] = q.z; ur[4 * j + 3] = q.w;
  }
  asm volatile("s_waitcnt lgkmcnt(0)" ::: "memory");
#pragma unroll
  for (int c = 0; c < 16; ++c) s[fb + c * 16 + b] = vi[c];
  asm volatile("s_waitcnt lgkmcnt(0)" ::: "memory");
#pragma unroll
  for (int j = 0; j < 4; ++j) {
    float4 q = *(const float4*)&s[rbase + 4 * j];
    ui[4 * j + 0] = q.x; ui[4 * j + 1] = q.y;
    ui[4 * j + 2] = q.z; ui[4 * j + 3] = q.w;
  }

  // Stage 2: row DFT-16 over b at fixed c (= this thread's b).
  dft16(ur, ui);

  // X[c + 16d] * 1/sqrt(256), direct reg -> global (nontemporal: zero reuse,
  // don't thrash L2/L3 with 0.5 GB of dead lines). Full 64B lines per instr.
  float* go_r = out + frame * 256 + b;
  float* go_i = out + half + frame * 256 + b;
#pragma unroll
  for (int d = 0; d < 16; ++d) {
    __builtin_nontemporal_store(ur[d] * 0.0625f, go_r + d * 16);
    __builtin_nontemporal_store(ui[d] * 0.0625f, go_i + d * 16);
  }
}

extern "C" void kernel_launch(void* const* d_in, const int* in_sizes, int n_in,
                              void* d_out, int out_size, void* d_ws, size_t ws_size,
                              hipStream_t stream) {
  const float* xr = (const float*)d_in[0];
  const float* xi = (const float*)d_in[1];
  // d_in[2]/d_in[3] (W_real/W_imag) intentionally unused: FFT twiddles are exact.
  float* out = (float*)d_out;
  const size_t half = (size_t)in_sizes[0];       // B*N = 67108864 floats
  const int blocks = (int)(half / 4096);         // 16 frames per 256-thread block
  dft256_kernel<<<blocks, 256, 0, stream>>>(xr, xi, out, half);
}

// Round 2
// 834.780 us; speedup vs baseline: 1.0167x; 1.0167x over previous
//
#include <hip/hip_runtime.h>
#include <math.h>

// Batched 256-point complex DFT as 16x16 four-step FFT.
// Round-2 synthesis: R0's proven global pattern (fully contiguous 1KB/wave
// float4 bursts, no NT) + R1's wave-private barrier-free structure, with ONE
// reused 16.9 KB LDS slice (real/imag and all three reshapes serialized
// through it per wave, ordered by lgkmcnt fences only - no s_barrier).
#define FS 264  // frame slice stride in floats: strided phases 2-way banked
                // (free), float4 phases stay 16B-aligned

__device__ __forceinline__ void dft16(float* xr, float* xi) {
  // 16-point DFT, natural-order in/out, radix-4 x radix-4.
  // Twiddles w16^k = cos(pi k/8) - i sin(pi k/8), k = b*c <= 9.
  constexpr float TWR[10] = {1.f, 0.9238795325f, 0.7071067812f, 0.3826834324f, 0.f,
                             -0.3826834324f, -0.7071067812f, -0.9238795325f, -1.f,
                             -0.9238795325f};
  constexpr float TWI[10] = {0.f, -0.3826834324f, -0.7071067812f, -0.9238795325f, -1.f,
                             -0.9238795325f, -0.7071067812f, -0.3826834324f, 0.f,
                             0.3826834324f};
  float yr[16], yi[16];
#pragma unroll
  for (int b = 0; b < 4; ++b) {
    float x0r = xr[b],      x0i = xi[b];
    float x1r = xr[b + 4],  x1i = xi[b + 4];
    float x2r = xr[b + 8],  x2i = xi[b + 8];
    float x3r = xr[b + 12], x3i = xi[b + 12];
    float t0r = x0r + x2r, t0i = x0i + x2i;
    float t1r = x0r - x2r, t1i = x0i - x2i;
    float t2r = x1r + x3r, t2i = x1i + x3i;
    float t3r = x1r - x3r, t3i = x1i - x3i;
    // store as y[c*4 + b]
    yr[0 + b]  = t0r + t2r;  yi[0 + b]  = t0i + t2i;   // c=0
    yr[8 + b]  = t0r - t2r;  yi[8 + b]  = t0i - t2i;   // c=2
    yr[4 + b]  = t1r + t3i;  yi[4 + b]  = t1i - t3r;   // c=1: t1 - i*t3
    yr[12 + b] = t1r - t3i;  yi[12 + b] = t1i + t3r;   // c=3: t1 + i*t3
  }
#pragma unroll
  for (int c = 0; c < 4; ++c) {
    float zr[4], zi[4];
#pragma unroll
    for (int b = 0; b < 4; ++b) {
      const int k = b * c;  // <= 9, compile-time after unroll
      float ar = yr[c * 4 + b], ai = yi[c * 4 + b];
      zr[b] = ar * TWR[k] - ai * TWI[k];
      zi[b] = ar * TWI[k] + ai * TWR[k];
    }
    float t0r = zr[0] + zr[2], t0i = zi[0] + zi[2];
    float t1r = zr[0] - zr[2], t1i = zi[0] - zi[2];
    float t2r = zr[1] + zr[3], t2i = zi[1] + zi[3];
    float t3r = zr[1] - zr[3], t3i = zi[1] - zi[3];
    // out[c + 4d]
    xr[c]      = t0r + t2r;  xi[c]      = t0i + t2i;   // d=0
    xr[c + 8]  = t0r - t2r;  xi[c + 8]  = t0i - t2i;   // d=2
    xr[c + 4]  = t1r + t3i;  xi[c + 4]  = t1i - t3r;   // d=1
    xr[c + 12] = t1r - t3i;  xi[c + 12] = t1i + t3r;   // d=3
  }
}

#define LFENCE asm volatile("s_waitcnt lgkmcnt(0)" ::: "memory")

__global__ __launch_bounds__(256, 4) void dft256_kernel(
    const float* __restrict__ xr, const float* __restrict__ xi,
    float* __restrict__ out, size_t half) {
  // Wave w owns frames 4w..4w+3 of this block: every LDS phase is
  // wave-private (lockstep wave64 -> only memory-order fences needed).
  __shared__ __align__(16) float s[16 * FS];
  const int t = threadIdx.x;
  const int w = t >> 6;   // wave 0..3
  const int l = t & 63;   // lane
  const int f = t >> 4;   // compute-role frame 0..15 (== 4w..4w+3 per wave)
  const int b = t & 15;   // compute-role column (stage1) / row c (stage2)
  const int fb = f * FS;
  // IO role: lane l handles float4 #l of frame (4w+i): row a=l>>2, chunk j=l&3
  const int io_slot = (w * 4) * FS + (l >> 2) * 16 + (l & 3) * 4;  // +i*FS per i
  const size_t blk4 = (size_t)blockIdx.x * 1024;  // block offset, float4 units
  const size_t wb4 = blk4 + (size_t)w * 256 + l;  // wave base + lane, +i*64/frame

  // ---- Issue ALL global loads up front: per instruction one wave reads a
  // fully contiguous 1KB frame (64 lanes x 16B) - R0's proven burst pattern.
  const float4* xr4 = (const float4*)xr;
  const float4* xi4 = (const float4*)xi;
  float4 R[4], I[4];
#pragma unroll
  for (int i = 0; i < 4; ++i) R[i] = xr4[wb4 + (size_t)i * 64];
#pragma unroll
  for (int i = 0; i < 4; ++i) I[i] = xi4[wb4 + (size_t)i * 64];

  float vr[16], vi[16];
  // ---- Real: rows -> slice (conflict-free b128) -> columns (2-way: free)
#pragma unroll
  for (int i = 0; i < 4; ++i) *(float4*)&s[io_slot + i * FS] = R[i];
  LFENCE;
#pragma unroll
  for (int a = 0; a < 16; ++a) vr[a] = s[fb + a * 16 + b];
  LFENCE;  // col reads done before slice reuse
  // ---- Imag through the same slice
#pragma unroll
  for (int i = 0; i < 4; ++i) *(float4*)&s[io_slot + i * FS] = I[i];
  LFENCE;
#pragma unroll
  for (int a = 0; a < 16; ++a) vi[a] = s[fb + a * 16 + b];

  // Stage 1: column DFT-16 over a at fixed b.
  dft16(vr, vi);

  // Twiddle Z[c] = Y[c] * w256^{b c}; base via one sincos, then chained cmul.
  float swb, cwb;
  __sincosf(-6.283185307179586f * (float)b * (1.0f / 256.0f), &swb, &cwb);
  float twr = 1.f, twi = 0.f;
#pragma unroll
  for (int c = 0; c < 16; ++c) {
    float ar = vr[c], ai = vi[c];
    vr[c] = ar * twr - ai * twi;
    vi[c] = ar * twi + ai * twr;
    float ntr = twr * cwb - twi * swb;
    twi = twr * swb + twi * cwb;
    twr = ntr;
  }

  // ---- Mid transpose: strided write (2-way: free) -> contiguous row read
  float ur[16], ui[16];
  LFENCE;  // imag col reads complete before overwrite
#pragma unroll
  for (int c = 0; c < 16; ++c) s[fb + c * 16 + b] = vr[c];
  LFENCE;
#pragma unroll
  for (int j = 0; j < 4; ++j) {
    float4 q = *(const float4*)&s[fb + b * 16 + 4 * j];
    ur[4 * j + 0] = q.x; ur[4 * j + 1] = q.y;
    ur[4 * j + 2] = q.z; ur[4 * j + 3] = q.w;
  }
  LFENCE;
#pragma unroll
  for (int c = 0; c < 16; ++c) s[fb + c * 16 + b] = vi[c];
  LFENCE;
#pragma unroll
  for (int j = 0; j < 4; ++j) {
    float4 q = *(const float4*)&s[fb + b * 16 + 4 * j];
    ui[4 * j + 0] = q.x; ui[4 * j + 1] = q.y;
    ui[4 * j + 2] = q.z; ui[4 * j + 3] = q.w;
  }

  // Stage 2: row DFT-16 over b at fixed c (= this thread's b).
  dft16(ur, ui);

  // ---- Output: X[c+16d]/16 strided into slice (natural order), contiguous
  // row read, fully contiguous 1KB float4 bursts to global. Real then imag.
  float4* outr4 = (float4*)out;
  float4* outi4 = (float4*)(out + half);
  LFENCE;  // row reads complete before overwrite
#pragma unroll
  for (int d = 0; d < 16; ++d) s[fb + d * 16 + b] = ur[d] * 0.0625f;
  LFENCE;
#pragma unroll
  for (int i = 0; i < 4; ++i) R[i] = *(const float4*)&s[io_slot + i * FS];
#pragma unroll
  for (int i = 0; i < 4; ++i) outr4[wb4 + (size_t)i * 64] = R[i];
  LFENCE;  // real row reads complete before imag overwrite
#pragma unroll
  for (int d = 0; d < 16; ++d) s[fb + d * 16 + b] = ui[d] * 0.0625f;
  LFENCE;
#pragma unroll
  for (int i = 0; i < 4; ++i) I[i] = *(const float4*)&s[io_slot + i * FS];
#pragma unroll
  for (int i = 0; i < 4; ++i) outi4[wb4 + (size_t)i * 64] = I[i];
}

extern "C" void kernel_launch(void* const* d_in, const int* in_sizes, int n_in,
                              void* d_out, int out_size, void* d_ws, size_t ws_size,
                              hipStream_t stream) {
  const float* xr = (const float*)d_in[0];
  const float* xi = (const float*)d_in[1];
  // d_in[2]/d_in[3] (W_real/W_imag) intentionally unused: FFT twiddles are exact.
  float* out = (float*)d_out;
  const size_t half = (size_t)in_sizes[0];       // B*N = 67108864 floats
  const int blocks = (int)(half / 4096);         // 16 frames per 256-thread block
  dft256_kernel<<<blocks, 256, 0, stream>>>(xr, xi, out, half);
}